// Round 1
// 631.451 us; speedup vs baseline: 1.0235x; 1.0235x over previous
//
#include <hip/hip_runtime.h>
#include <hip/hip_fp16.h>
#include <math.h>

#define N_NODES 50000
#define E_EDGES 800000
#define E2 (E_EDGES + N_NODES)
#define HID 128
#define HEADS 4
#define OUTC 64
#define DEPTH 4
#define NEG_SLOPE 0.2f
#define LN_EPS 1e-6f
#define NT2 3125          // 16-row tiles (50000/16 exactly)

typedef float f32x4 __attribute__((ext_vector_type(4)));
typedef float f32x2 __attribute__((ext_vector_type(2)));
typedef _Float16 half8 __attribute__((ext_vector_type(8)));

// ---------------- CSR build ----------------

__global__ void k_deg(const int* __restrict__ ei, int* __restrict__ deg) {
    int e = blockIdx.x * 256 + threadIdx.x;
    if (e >= E2) return;
    int d = (e < E_EDGES) ? ei[E_EDGES + e] : (e - E_EDGES);
    atomicAdd(&deg[d], 1);
}

__global__ void k_scan_block(const int* __restrict__ deg, int* __restrict__ partial,
                             int* __restrict__ bsum, int n) {
    __shared__ int sm[1024];
    int i = blockIdx.x * 1024 + threadIdx.x;
    int v = (i < n) ? deg[i] : 0;
    sm[threadIdx.x] = v;
    __syncthreads();
    for (int off = 1; off < 1024; off <<= 1) {
        int t = (threadIdx.x >= off) ? sm[threadIdx.x - off] : 0;
        __syncthreads();
        sm[threadIdx.x] += t;
        __syncthreads();
    }
    if (i < n) partial[i] = sm[threadIdx.x];
    if (threadIdx.x == 1023) bsum[blockIdx.x] = sm[1023];
}

__global__ void k_scan_bsum(int* __restrict__ bsum, int nb) {
    if (threadIdx.x == 0 && blockIdx.x == 0) {
        int run = 0;
        for (int b = 0; b < nb; ++b) { int v = bsum[b]; bsum[b] = run; run += v; }
    }
}

__global__ void k_scan_fix(const int* __restrict__ deg, int* __restrict__ row_ptr,
                           const int* __restrict__ bsum, int n) {
    int i = blockIdx.x * 1024 + threadIdx.x;
    if (i < n) row_ptr[i] = row_ptr[i] - deg[i] + bsum[blockIdx.x];
    if (i == 0) row_ptr[n] = E2;
}

__global__ void k_fill(const int* __restrict__ ei, const int* __restrict__ row_ptr,
                       int* __restrict__ cur, int* __restrict__ csr_src,
                       int* __restrict__ csr_dst) {
    int e = blockIdx.x * 256 + threadIdx.x;
    if (e >= E2) return;
    int s, d;
    if (e < E_EDGES) { s = ei[e]; d = ei[E_EDGES + e]; } else { s = d = e - E_EDGES; }
    int pos = atomicAdd(&cur[d], 1);
    int j = row_ptr[d] + pos;
    csr_src[j] = s;
    csr_dst[j] = d;
}

// ---------------- ws[layer][c][j]: fused attention weights: ws = W . att ----------------

__global__ void k_ws(const float* __restrict__ W_conv, const float* __restrict__ att_s,
                     const float* __restrict__ att_d, float* __restrict__ ws_all) {
    int idx = blockIdx.x * 256 + threadIdx.x;
    if (idx >= DEPTH * 1024) return;
    int j = idx & 7, c = (idx >> 3) & 127, layer = idx >> 10;
    int hh = j & 3, sd = j >> 2;
    const float* Wr = W_conv + (size_t)layer * 65536 + (size_t)c * 512 + hh * HID;
    const float* at = (sd ? att_d : att_s) + (size_t)layer * HEADS * HID + hh * HID;
    float s = 0.f;
    for (int cc = 0; cc < HID; ++cc) s += Wr[cc] * at[cc];
    ws_all[idx] = s;
}

// ---------------- repack W_conv into gemm2 B-frags: B''[k=h*128+s][n] = W[c(s), h*128+n]/4 ----
// storage perm: s = l15*8 + nt  ->  logical channel c = (s&7)*16 + (s>>3)

__global__ void k_repackB2(const float* __restrict__ W_conv, _Float16* __restrict__ Bp) {
    int idx = blockIdx.x * 256 + threadIdx.x;
    if (idx >= DEPTH * 65536) return;
    int jj    = idx & 7;
    int lane  = (idx >> 3) & 63;
    int kc    = (idx >> 9) & 15;
    int ntile = (idx >> 13) & 7;
    int layer = idx >> 16;
    int k = kc * 32 + (lane >> 4) * 8 + jj;
    int n = ntile * 16 + (lane & 15);
    int hh = k >> 7;
    int s  = k & 127;
    int c  = (s & 7) * 16 + (s >> 3);
    Bp[idx] = (_Float16)(0.25f * W_conv[(size_t)layer * 65536 + (size_t)c * 512 + hh * HID + n]);
}

// ---------------- repack W_out into out-proj B-frags (same channel perm, fp16) -----------
// Bout[((kc*4+nt)*64+lane)*8+j] = W_out[c(k)][nt*16+(lane&15)], k = kc*32+(lane>>4)*8+j

__global__ void k_repackBout(const float* __restrict__ W_out, _Float16* __restrict__ Bout) {
    int idx = blockIdx.x * 256 + threadIdx.x;
    if (idx >= 8192) return;
    int j    = idx & 7;
    int lane = (idx >> 3) & 63;
    int nt   = (idx >> 9) & 3;
    int kc   = idx >> 11;
    int k = kc * 32 + (lane >> 4) * 8 + j;
    int c = (k & 7) * 16 + (k >> 3);
    int n = nt * 16 + (lane & 15);
    Bout[idx] = (_Float16)W_out[(size_t)c * OUTC + n];
}

// ---------------- input projection + LN -> fp8 ln table (perm layout) + layer-0 alphas ----------------

__global__ __launch_bounds__(256) void k_in_proj_ln(const float* __restrict__ x,
                                                    const float* __restrict__ W,
                                                    const float* __restrict__ bias,
                                                    const float* __restrict__ gamma,
                                                    const float* __restrict__ beta,
                                                    const float* __restrict__ ws,
                                                    float* __restrict__ h,
                                                    unsigned char* __restrict__ ln8,
                                                    float* __restrict__ as_,
                                                    float* __restrict__ ad_) {
    int tid = threadIdx.x;
    int lane = tid & 63;
    int nd = blockIdx.x * 4 + (tid >> 6);
    const float* xr = x + nd * 3;
    float x0 = xr[0], x1 = xr[1], x2 = xr[2];
    int j0 = lane, j1 = lane + 64;
    float a = bias[j0] + x0 * W[j0] + x1 * W[HID + j0] + x2 * W[2 * HID + j0];
    float b = bias[j1] + x0 * W[j1] + x1 * W[HID + j1] + x2 * W[2 * HID + j1];
    size_t base = (size_t)nd * HID;
    h[base + j0] = a;
    h[base + j1] = b;
    float s = a + b;
    for (int o = 1; o < 64; o <<= 1) s += __shfl_xor(s, o);
    float mu = s * (1.0f / 128.0f);
    float da = a - mu, db = b - mu;
    float v = da * da + db * db;
    for (int o = 1; o < 64; o <<= 1) v += __shfl_xor(v, o);
    float rstd = rsqrtf(v * (1.0f / 128.0f) + LN_EPS);
    float va = da * rstd * gamma[j0] + beta[j0];
    float vb = db * rstd * gamma[j1] + beta[j1];

    // layer-0 alphas
    float ap[8];
    for (int j = 0; j < 8; ++j)
        ap[j] = va * ws[j0 * 8 + j] + vb * ws[j1 * 8 + j];
    for (int o = 1; o < 64; o <<= 1)
        for (int j = 0; j < 8; ++j) ap[j] += __shfl_xor(ap[j], o);
    if (lane == 0) {
        for (int hh = 0; hh < 4; ++hh) {
            as_[nd * 4 + hh] = ap[hh];
            ad_[nd * 4 + hh] = ap[4 + hh];
        }
    }

    // fp8 table write (perm layout): storage s = lane*8 + t holds logical channel c = t*16 + lane
    float pv[8];
    for (int t = 0; t < 8; ++t) {
        int c = t * 16 + (lane & 15);
        float s1 = __shfl(va, c & 63);
        float s2 = __shfl(vb, c & 63);
        pv[t] = (c < 64) ? s1 : s2;
    }
    if (lane < 16) {
        int w0 = __builtin_amdgcn_cvt_pk_fp8_f32(pv[0], pv[1], 0, false);
        w0     = __builtin_amdgcn_cvt_pk_fp8_f32(pv[2], pv[3], w0, true);
        int w1 = __builtin_amdgcn_cvt_pk_fp8_f32(pv[4], pv[5], 0, false);
        w1     = __builtin_amdgcn_cvt_pk_fp8_f32(pv[6], pv[7], w1, true);
        *(int2*)(ln8 + base + lane * 8) = make_int2(w0, w1);
    }
}

// ---------------- per-edge softmax numerators ----------------

__global__ __launch_bounds__(256) void k_edge(const int* __restrict__ csr_src,
                                              const int* __restrict__ csr_dst,
                                              const float* __restrict__ as_,
                                              const float* __restrict__ ad_,
                                              float* __restrict__ p) {
    int j = blockIdx.x * 256 + threadIdx.x;
    if (j >= E2) return;
    int s = csr_src[j];
    int d = csr_dst[j];
    float4 a4 = *(const float4*)(as_ + (size_t)s * 4);
    float4 b4 = *(const float4*)(ad_ + (size_t)d * 4);
    float4 r;
    float v;
    v = a4.x + b4.x; v = (v >= 0.f) ? v : NEG_SLOPE * v; r.x = __expf(v);
    v = a4.y + b4.y; v = (v >= 0.f) ? v : NEG_SLOPE * v; r.y = __expf(v);
    v = a4.z + b4.z; v = (v >= 0.f) ? v : NEG_SLOPE * v; r.z = __expf(v);
    v = a4.w + b4.w; v = (v >= 0.f) ? v : NEG_SLOPE * v; r.w = __expf(v);
    *(float4*)(p + (size_t)j * 4) = r;
}

// ---------------- per-node aggregate of fp8 LN rows; 1 wave per node; A-frag output ----------------
// agg frag layout: [tile][kc(16)][fraglane(64)][j(8)] fp16.
// Lane owns channels k = h*128 + lane*2 + {0,1}:
//   kc = h*4 + (lane>>4), fraglane = ((lane&15)>>2)*16 + (nd&15), j0 = 2*(lane&3).

__global__ __launch_bounds__(256) void k_agg(const unsigned char* __restrict__ ln8,
                                             const float* __restrict__ p,
                                             const int* __restrict__ row_ptr,
                                             const int* __restrict__ csr_src,
                                             _Float16* __restrict__ agg) {
    int tid = threadIdx.x;
    int lane = tid & 63;
    int nd = blockIdx.x * 4 + (tid >> 6);
    int e = row_ptr[nd], end = row_ptr[nd + 1];

    f32x2 ac0 = (f32x2)(0.f), ac1 = (f32x2)(0.f), ac2 = (f32x2)(0.f), ac3 = (f32x2)(0.f);
    float z0 = 0.f, z1 = 0.f, z2 = 0.f, z3 = 0.f;
    const unsigned char* xbase = ln8 + lane * 2;

    for (; e + 4 <= end; e += 4) {
        int src0 = csr_src[e], src1 = csr_src[e + 1], src2 = csr_src[e + 2], src3 = csr_src[e + 3];
        float4 p0 = *(const float4*)(p + (size_t)(e + 0) * 4);
        float4 p1 = *(const float4*)(p + (size_t)(e + 1) * 4);
        float4 p2 = *(const float4*)(p + (size_t)(e + 2) * 4);
        float4 p3 = *(const float4*)(p + (size_t)(e + 3) * 4);
        unsigned short w0 = *(const unsigned short*)(xbase + (size_t)src0 * 128);
        unsigned short w1 = *(const unsigned short*)(xbase + (size_t)src1 * 128);
        unsigned short w2 = *(const unsigned short*)(xbase + (size_t)src2 * 128);
        unsigned short w3 = *(const unsigned short*)(xbase + (size_t)src3 * 128);
        f32x2 v0 = __builtin_amdgcn_cvt_pk_f32_fp8((int)w0, false);
        f32x2 v1 = __builtin_amdgcn_cvt_pk_f32_fp8((int)w1, false);
        f32x2 v2 = __builtin_amdgcn_cvt_pk_f32_fp8((int)w2, false);
        f32x2 v3 = __builtin_amdgcn_cvt_pk_f32_fp8((int)w3, false);
        ac0 += (f32x2)(p0.x) * v0 + (f32x2)(p1.x) * v1 + (f32x2)(p2.x) * v2 + (f32x2)(p3.x) * v3;
        ac1 += (f32x2)(p0.y) * v0 + (f32x2)(p1.y) * v1 + (f32x2)(p2.y) * v2 + (f32x2)(p3.y) * v3;
        ac2 += (f32x2)(p0.z) * v0 + (f32x2)(p1.z) * v1 + (f32x2)(p2.z) * v2 + (f32x2)(p3.z) * v3;
        ac3 += (f32x2)(p0.w) * v0 + (f32x2)(p1.w) * v1 + (f32x2)(p2.w) * v2 + (f32x2)(p3.w) * v3;
        z0 += (p0.x + p1.x) + (p2.x + p3.x);
        z1 += (p0.y + p1.y) + (p2.y + p3.y);
        z2 += (p0.z + p1.z) + (p2.z + p3.z);
        z3 += (p0.w + p1.w) + (p2.w + p3.w);
    }
    for (; e < end; ++e) {
        int src0 = csr_src[e];
        float4 p0 = *(const float4*)(p + (size_t)e * 4);
        unsigned short w0 = *(const unsigned short*)(xbase + (size_t)src0 * 128);
        f32x2 v0 = __builtin_amdgcn_cvt_pk_f32_fp8((int)w0, false);
        ac0 += (f32x2)(p0.x) * v0;
        ac1 += (f32x2)(p0.y) * v0;
        ac2 += (f32x2)(p0.z) * v0;
        ac3 += (f32x2)(p0.w) * v0;
        z0 += p0.x; z1 += p0.y; z2 += p0.z; z3 += p0.w;
    }

    ac0 *= (f32x2)(1.0f / z0);
    ac1 *= (f32x2)(1.0f / z1);
    ac2 *= (f32x2)(1.0f / z2);
    ac3 *= (f32x2)(1.0f / z3);

    // frag-layout packed stores (4B = 2 fp16 per head)
    int tile = nd >> 4, m = nd & 15;
    int kcb  = lane >> 4;                     // kc = h*4 + kcb
    int fraglane = ((lane & 15) >> 2) * 16 + m;
    int j0 = 2 * (lane & 3);
    union { _Float16 hx[2]; unsigned int u; } cv;
    size_t tb = (size_t)tile * 16;
    cv.hx[0] = (_Float16)ac0[0]; cv.hx[1] = (_Float16)ac0[1];
    *(unsigned int*)(agg + ((tb + 0 * 4 + kcb) * 64 + fraglane) * 8 + j0) = cv.u;
    cv.hx[0] = (_Float16)ac1[0]; cv.hx[1] = (_Float16)ac1[1];
    *(unsigned int*)(agg + ((tb + 1 * 4 + kcb) * 64 + fraglane) * 8 + j0) = cv.u;
    cv.hx[0] = (_Float16)ac2[0]; cv.hx[1] = (_Float16)ac2[1];
    *(unsigned int*)(agg + ((tb + 2 * 4 + kcb) * 64 + fraglane) * 8 + j0) = cv.u;
    cv.hx[0] = (_Float16)ac3[0]; cv.hx[1] = (_Float16)ac3[1];
    *(unsigned int*)(agg + ((tb + 3 * 4 + kcb) * 64 + fraglane) * 8 + j0) = cv.u;
}

// ---------------- gemm2: agg(frag) x B''(LDS-staged) -> epilogue -> h, ln8, alphas ----------------
// 4 waves/block, one 16-row tile each; per-kc 8KB B slice staged in LDS and shared.
// last=1 (final layer): skip fp32 h write; emit h as fp16 MFMA A-frags for out-proj
// (same channel perm c(s) = (s&7)*16 + (s>>3); epilogue lane's 8 channels nt*16+l15
//  are exactly one frag octet -> one 16B store per row, no shuffles).

__global__ __launch_bounds__(256) void k_gemm2(const _Float16* __restrict__ agg,
                                               const _Float16* __restrict__ Bp,
                                               const float* __restrict__ ws,
                                               const float* __restrict__ bias,
                                               const float* __restrict__ gamma,
                                               const float* __restrict__ beta,
                                               float* __restrict__ h,
                                               unsigned char* __restrict__ ln8,
                                               float* __restrict__ as_,
                                               float* __restrict__ ad_,
                                               _Float16* __restrict__ h16,
                                               int write_ln, int last) {
    __shared__ _Float16 Bs[4096];       // 8 KB: [nt(8)][lane(64)][j(8)]
    int tid = threadIdx.x;
    int lane = tid & 63;
    int w = tid >> 6;
    int tile = blockIdx.x * 4 + w;
    int valid = (tile < NT2);
    if (!valid) tile = 0;               // stay for barriers; all global writes guarded
    int quad = lane >> 4;
    int l15  = lane & 15;

    // staging indices: thread covers 16 fp16 (32 B) of the 8 KB slice
    int ntS  = tid >> 5;
    int remS = (tid & 31) * 16;

    f32x4 acc[8];
    for (int nt = 0; nt < 8; ++nt) acc[nt] = (f32x4)(0.0f);

    const _Float16* abase = agg + (size_t)tile * 8192 + lane * 8;
    for (int kc = 0; kc < 16; ++kc) {
        half8 a = *(const half8*)(abase + kc * 512);          // global, independent of LDS
        const _Float16* src = Bp + ((size_t)(ntS * 16 + kc)) * 512 + remS;
        __syncthreads();                                      // prior kc's reads done
        *(half8*)(Bs + tid * 16)     = *(const half8*)(src);
        *(half8*)(Bs + tid * 16 + 8) = *(const half8*)(src + 8);
        __syncthreads();                                      // slice visible
        for (int nt = 0; nt < 8; ++nt) {
            half8 b = *(const half8*)(Bs + nt * 512 + lane * 8);
            acc[nt] = __builtin_amdgcn_mfma_f32_16x16x32_f16(a, b, acc[nt], 0, 0, 0);
        }
    }

    if (!valid) return;                 // no barriers below

    int row0 = tile * 16;
    float bi[8];
    for (int nt = 0; nt < 8; ++nt) bi[nt] = bias[nt * 16 + l15];
    float ga[8], be[8], wsv[8][8];
    if (write_ln) {
        for (int nt = 0; nt < 8; ++nt) {
            int c = nt * 16 + l15;
            ga[nt] = gamma[c];
            be[nt] = beta[c];
            for (int j = 0; j < 8; ++j) wsv[nt][j] = ws[c * 8 + j];
        }
    }

    for (int r = 0; r < 4; ++r) {
        int node = row0 + quad * 4 + r;
        float* hr = h + (size_t)node * HID;
        float rv[8];
        for (int nt = 0; nt < 8; ++nt) {
            float t = acc[nt][r] + bi[nt];
            t = fmaxf(t, 0.f);
            rv[nt] = t + hr[nt * 16 + l15];
        }
        if (!last) {
            for (int nt = 0; nt < 8; ++nt) hr[nt * 16 + l15] = rv[nt];
        } else {
            // fp16 A-frag emit: kc = l15>>2, fraglane = (l15&3)*16 + quad*4 + r, j = nt
            union { _Float16 hx[8]; int4 v4; } cf;
            for (int nt = 0; nt < 8; ++nt) cf.hx[nt] = (_Float16)rv[nt];
            int kc = l15 >> 2;
            int lf = (l15 & 3) * 16 + quad * 4 + r;
            *(int4*)(h16 + (((size_t)tile * 4 + kc) * 64 + lf) * 8) = cf.v4;
        }

        if (write_ln) {
            float s = 0.f;
            for (int nt = 0; nt < 8; ++nt) s += rv[nt];
            s += __shfl_xor(s, 1); s += __shfl_xor(s, 2);
            s += __shfl_xor(s, 4); s += __shfl_xor(s, 8);
            float mu = s * (1.0f / 128.0f);
            float var = 0.f;
            for (int nt = 0; nt < 8; ++nt) { float d = rv[nt] - mu; var += d * d; }
            var += __shfl_xor(var, 1); var += __shfl_xor(var, 2);
            var += __shfl_xor(var, 4); var += __shfl_xor(var, 8);
            float rstd = rsqrtf(var * (1.0f / 128.0f) + LN_EPS);
            float lnv[8];
            for (int nt = 0; nt < 8; ++nt)
                lnv[nt] = (rv[nt] - mu) * rstd * ga[nt] + be[nt];

            float ap[8];
            for (int j = 0; j < 8; ++j) {
                float t = 0.f;
                for (int nt = 0; nt < 8; ++nt) t += lnv[nt] * wsv[nt][j];
                ap[j] = t;
            }
            for (int j = 0; j < 8; ++j) {
                ap[j] += __shfl_xor(ap[j], 1); ap[j] += __shfl_xor(ap[j], 2);
                ap[j] += __shfl_xor(ap[j], 4); ap[j] += __shfl_xor(ap[j], 8);
            }
            if (l15 == 0) {
                for (int hh = 0; hh < 4; ++hh) {
                    as_[node * 4 + hh] = ap[hh];
                    ad_[node * 4 + hh] = ap[4 + hh];
                }
            }

            int w0 = __builtin_amdgcn_cvt_pk_fp8_f32(lnv[0], lnv[1], 0, false);
            w0     = __builtin_amdgcn_cvt_pk_fp8_f32(lnv[2], lnv[3], w0, true);
            int w1 = __builtin_amdgcn_cvt_pk_fp8_f32(lnv[4], lnv[5], 0, false);
            w1     = __builtin_amdgcn_cvt_pk_fp8_f32(lnv[6], lnv[7], w1, true);
            *(int2*)(ln8 + (size_t)node * 128 + l15 * 8) = make_int2(w0, w1);
        }
    }
}

// ---------------- output projection: fp16 MFMA streaming GEMM, 1 wave per 16-node tile ----
// A = h16 frags (written by last-layer gemm2), B = repacked W_out (16 KB, L1-resident).
// No LDS, low VGPR -> high occupancy; memory-bound on 12.8 MB read + 12.8 MB write.

__global__ __launch_bounds__(256) void k_out_proj_mfma(const _Float16* __restrict__ h16,
                                                       const _Float16* __restrict__ Bout,
                                                       const float* __restrict__ b,
                                                       float* __restrict__ out) {
    int tid = threadIdx.x;
    int lane = tid & 63;
    int tile = blockIdx.x * 4 + (tid >> 6);
    if (tile >= NT2) return;

    const _Float16* ab = h16 + (size_t)tile * 2048 + lane * 8;
    f32x4 acc[4];
    for (int nt = 0; nt < 4; ++nt) acc[nt] = (f32x4)(0.0f);
    #pragma unroll
    for (int kc = 0; kc < 4; ++kc) {
        half8 a = *(const half8*)(ab + kc * 512);
        #pragma unroll
        for (int nt = 0; nt < 4; ++nt) {
            half8 bf = *(const half8*)(Bout + ((size_t)(kc * 4 + nt) * 64 + lane) * 8);
            acc[nt] = __builtin_amdgcn_mfma_f32_16x16x32_f16(a, bf, acc[nt], 0, 0, 0);
        }
    }

    int l15 = lane & 15, quad = lane >> 4;
    float bo[4];
    #pragma unroll
    for (int nt = 0; nt < 4; ++nt) bo[nt] = b[nt * 16 + l15];
    #pragma unroll
    for (int r = 0; r < 4; ++r) {
        int node = tile * 16 + quad * 4 + r;
        float* orow = out + (size_t)node * OUTC;
        #pragma unroll
        for (int nt = 0; nt < 4; ++nt)
            orow[nt * 16 + l15] = acc[nt][r] + bo[nt];
    }
}

// ---------------- launch ----------------

extern "C" void kernel_launch(void* const* d_in, const int* in_sizes, int n_in,
                              void* d_out, int out_size, void* d_ws, size_t ws_size,
                              hipStream_t stream) {
    const float* x       = (const float*)d_in[0];
    const int*   ei      = (const int*)d_in[1];
    const float* W_in    = (const float*)d_in[2];
    const float* b_in    = (const float*)d_in[3];
    const float* W_conv  = (const float*)d_in[4];
    const float* att_src = (const float*)d_in[5];
    const float* att_dst = (const float*)d_in[6];
    const float* b_conv  = (const float*)d_in[7];
    const float* ln_g    = (const float*)d_in[8];
    const float* ln_b    = (const float*)d_in[9];
    const float* W_out   = (const float*)d_in[10];
    const float* b_out   = (const float*)d_in[11];
    float* out = (float*)d_out;

    char* ws = (char*)d_ws;
    size_t off = 0;
    auto alloc = [&](size_t bytes) { void* p = ws + off; off = (off + bytes + 255) & ~(size_t)255; return p; };
    float* h            = (float*)alloc((size_t)N_NODES * HID * 4);
    _Float16* agg       = (_Float16*)alloc((size_t)NT2 * 8192 * 2);   // frag layout
    unsigned char* ln8  = (unsigned char*)alloc((size_t)N_NODES * 128);
    float* as_          = (float*)alloc((size_t)N_NODES * 4 * 4);
    float* ad_          = (float*)alloc((size_t)N_NODES * 4 * 4);
    float* pedge        = (float*)alloc((size_t)E2 * HEADS * 4);
    _Float16* Bp2       = (_Float16*)alloc((size_t)DEPTH * 65536 * 2);
    float* ws_all       = (float*)alloc((size_t)DEPTH * 1024 * 4);
    _Float16* h16       = (_Float16*)alloc((size_t)NT2 * 2048 * 2);   // out-proj A-frags
    _Float16* Bout      = (_Float16*)alloc((size_t)8192 * 2);         // out-proj B-frags
    int* deg    = (int*)alloc((size_t)N_NODES * 4);
    int* cur    = (int*)alloc((size_t)N_NODES * 4);
    int* row_ptr= (int*)alloc((size_t)(N_NODES + 1) * 4);
    int* csr    = (int*)alloc((size_t)E2 * 4);
    int* csrd   = (int*)alloc((size_t)E2 * 4);
    int* bsum   = (int*)alloc(256 * 4);
    (void)ws_size; (void)n_in; (void)in_sizes; (void)out_size;

    hipMemsetAsync(deg, 0, (size_t)N_NODES * 4, stream);
    hipMemsetAsync(cur, 0, (size_t)N_NODES * 4, stream);

    // CSR build
    k_deg<<<(E2 + 255) / 256, 256, 0, stream>>>(ei, deg);
    int nb = (N_NODES + 1023) / 1024;
    k_scan_block<<<nb, 1024, 0, stream>>>(deg, row_ptr, bsum, N_NODES);
    k_scan_bsum<<<1, 64, 0, stream>>>(bsum, nb);
    k_scan_fix<<<nb, 1024, 0, stream>>>(deg, row_ptr, bsum, N_NODES);
    k_fill<<<(E2 + 255) / 256, 256, 0, stream>>>(ei, row_ptr, cur, csr, csrd);

    // weight preprocessing (per call; graph-safe)
    k_ws<<<(DEPTH * 1024 + 255) / 256, 256, 0, stream>>>(W_conv, att_src, att_dst, ws_all);
    k_repackB2<<<(DEPTH * 65536 + 255) / 256, 256, 0, stream>>>(W_conv, Bp2);
    k_repackBout<<<32, 256, 0, stream>>>(W_out, Bout);

    // input projection + first LN (fp8 table + layer-0 alphas)
    k_in_proj_ln<<<N_NODES / 4, 256, 0, stream>>>(x, W_in, b_in, ln_g, ln_b, ws_all,
                                                  h, ln8, as_, ad_);

    // layers
    for (int i = 0; i < DEPTH; ++i) {
        const float* bcp = b_conv + (size_t)i * HID;
        int write_ln = (i + 1 < DEPTH) ? 1 : 0;
        int last = (i + 1 == DEPTH) ? 1 : 0;
        int nl = (i + 1 < DEPTH) ? i + 1 : i;
        const float* gp = ln_g + (size_t)nl * HID;
        const float* bp = ln_b + (size_t)nl * HID;
        const float* wsp = ws_all + (size_t)nl * 1024;

        k_edge<<<(E2 + 255) / 256, 256, 0, stream>>>(csr, csrd, as_, ad_, pedge);
        k_agg<<<N_NODES / 4, 256, 0, stream>>>(ln8, pedge, row_ptr, csr, agg);
        k_gemm2<<<(NT2 + 3) / 4, 256, 0, stream>>>(agg, Bp2 + (size_t)i * 65536, wsp,
                                                   bcp, gp, bp, h, ln8, as_, ad_,
                                                   h16, write_ln, last);
    }

    k_out_proj_mfma<<<(NT2 + 3) / 4, 256, 0, stream>>>(h16, Bout, b_out, out);
}

// Round 2
// 618.261 us; speedup vs baseline: 1.0453x; 1.0213x over previous
//
#include <hip/hip_runtime.h>
#include <hip/hip_fp16.h>
#include <math.h>

#define N_NODES 50000
#define E_EDGES 800000
#define E2 (E_EDGES + N_NODES)
#define HID 128
#define HEADS 4
#define OUTC 64
#define DEPTH 4
#define NEG_SLOPE 0.2f
#define LN_EPS 1e-6f
#define NT2 3125          // 16-row tiles (50000/16 exactly)

typedef float f32x4 __attribute__((ext_vector_type(4)));
typedef float f32x2 __attribute__((ext_vector_type(2)));
typedef _Float16 half8 __attribute__((ext_vector_type(8)));

// ---------------- CSR build ----------------

__global__ void k_deg(const int* __restrict__ ei, int* __restrict__ deg) {
    int e = blockIdx.x * 256 + threadIdx.x;
    if (e >= E2) return;
    int d = (e < E_EDGES) ? ei[E_EDGES + e] : (e - E_EDGES);
    atomicAdd(&deg[d], 1);
}

__global__ void k_scan_block(const int* __restrict__ deg, int* __restrict__ partial,
                             int* __restrict__ bsum, int n) {
    __shared__ int sm[1024];
    int i = blockIdx.x * 1024 + threadIdx.x;
    int v = (i < n) ? deg[i] : 0;
    sm[threadIdx.x] = v;
    __syncthreads();
    for (int off = 1; off < 1024; off <<= 1) {
        int t = (threadIdx.x >= off) ? sm[threadIdx.x - off] : 0;
        __syncthreads();
        sm[threadIdx.x] += t;
        __syncthreads();
    }
    if (i < n) partial[i] = sm[threadIdx.x];
    if (threadIdx.x == 1023) bsum[blockIdx.x] = sm[1023];
}

__global__ void k_scan_bsum(int* __restrict__ bsum, int nb) {
    if (threadIdx.x == 0 && blockIdx.x == 0) {
        int run = 0;
        for (int b = 0; b < nb; ++b) { int v = bsum[b]; bsum[b] = run; run += v; }
    }
}

__global__ void k_scan_fix(const int* __restrict__ deg, int* __restrict__ row_ptr,
                           const int* __restrict__ bsum, int n) {
    int i = blockIdx.x * 1024 + threadIdx.x;
    if (i < n) row_ptr[i] = row_ptr[i] - deg[i] + bsum[blockIdx.x];
    if (i == 0) row_ptr[n] = E2;
}

__global__ void k_fill(const int* __restrict__ ei, const int* __restrict__ row_ptr,
                       int* __restrict__ cur, int* __restrict__ csr_src) {
    int e = blockIdx.x * 256 + threadIdx.x;
    if (e >= E2) return;
    int s, d;
    if (e < E_EDGES) { s = ei[e]; d = ei[E_EDGES + e]; } else { s = d = e - E_EDGES; }
    int pos = atomicAdd(&cur[d], 1);
    csr_src[row_ptr[d] + pos] = s;
}

// ---------------- ws[layer][c][j]: fused attention weights: ws = W . att ----------------

__global__ void k_ws(const float* __restrict__ W_conv, const float* __restrict__ att_s,
                     const float* __restrict__ att_d, float* __restrict__ ws_all) {
    int idx = blockIdx.x * 256 + threadIdx.x;
    if (idx >= DEPTH * 1024) return;
    int j = idx & 7, c = (idx >> 3) & 127, layer = idx >> 10;
    int hh = j & 3, sd = j >> 2;
    const float* Wr = W_conv + (size_t)layer * 65536 + (size_t)c * 512 + hh * HID;
    const float* at = (sd ? att_d : att_s) + (size_t)layer * HEADS * HID + hh * HID;
    float s = 0.f;
    for (int cc = 0; cc < HID; ++cc) s += Wr[cc] * at[cc];
    ws_all[idx] = s;
}

// ---------------- repack W_conv into gemm2 B-frags: B''[k=h*128+s][n] = W[c(s), h*128+n]/4 ----
// storage perm: s = l15*8 + nt  ->  logical channel c = (s&7)*16 + (s>>3)

__global__ void k_repackB2(const float* __restrict__ W_conv, _Float16* __restrict__ Bp) {
    int idx = blockIdx.x * 256 + threadIdx.x;
    if (idx >= DEPTH * 65536) return;
    int jj    = idx & 7;
    int lane  = (idx >> 3) & 63;
    int kc    = (idx >> 9) & 15;
    int ntile = (idx >> 13) & 7;
    int layer = idx >> 16;
    int k = kc * 32 + (lane >> 4) * 8 + jj;
    int n = ntile * 16 + (lane & 15);
    int hh = k >> 7;
    int s  = k & 127;
    int c  = (s & 7) * 16 + (s >> 3);
    Bp[idx] = (_Float16)(0.25f * W_conv[(size_t)layer * 65536 + (size_t)c * 512 + hh * HID + n]);
}

// ---------------- repack W_out into out-proj B-frags (same channel perm, fp16) -----------

__global__ void k_repackBout(const float* __restrict__ W_out, _Float16* __restrict__ Bout) {
    int idx = blockIdx.x * 256 + threadIdx.x;
    if (idx >= 8192) return;
    int j    = idx & 7;
    int lane = (idx >> 3) & 63;
    int nt   = (idx >> 9) & 3;
    int kc   = idx >> 11;
    int k = kc * 32 + (lane >> 4) * 8 + j;
    int c = (k & 7) * 16 + (k >> 3);
    int n = nt * 16 + (lane & 15);
    Bout[idx] = (_Float16)W_out[(size_t)c * OUTC + n];
}

// ---------------- input projection + LN -> fp8 ln table (perm layout) + layer-0 alphas ----------------

__global__ __launch_bounds__(256) void k_in_proj_ln(const float* __restrict__ x,
                                                    const float* __restrict__ W,
                                                    const float* __restrict__ bias,
                                                    const float* __restrict__ gamma,
                                                    const float* __restrict__ beta,
                                                    const float* __restrict__ ws,
                                                    float* __restrict__ h,
                                                    unsigned char* __restrict__ ln8,
                                                    float* __restrict__ as_,
                                                    float* __restrict__ ad_) {
    int tid = threadIdx.x;
    int lane = tid & 63;
    int nd = blockIdx.x * 4 + (tid >> 6);
    const float* xr = x + nd * 3;
    float x0 = xr[0], x1 = xr[1], x2 = xr[2];
    int j0 = lane, j1 = lane + 64;
    float a = bias[j0] + x0 * W[j0] + x1 * W[HID + j0] + x2 * W[2 * HID + j0];
    float b = bias[j1] + x0 * W[j1] + x1 * W[HID + j1] + x2 * W[2 * HID + j1];
    size_t base = (size_t)nd * HID;
    h[base + j0] = a;
    h[base + j1] = b;
    float s = a + b;
    for (int o = 1; o < 64; o <<= 1) s += __shfl_xor(s, o);
    float mu = s * (1.0f / 128.0f);
    float da = a - mu, db = b - mu;
    float v = da * da + db * db;
    for (int o = 1; o < 64; o <<= 1) v += __shfl_xor(v, o);
    float rstd = rsqrtf(v * (1.0f / 128.0f) + LN_EPS);
    float va = da * rstd * gamma[j0] + beta[j0];
    float vb = db * rstd * gamma[j1] + beta[j1];

    // layer-0 alphas
    float ap[8];
    for (int j = 0; j < 8; ++j)
        ap[j] = va * ws[j0 * 8 + j] + vb * ws[j1 * 8 + j];
    for (int o = 1; o < 64; o <<= 1)
        for (int j = 0; j < 8; ++j) ap[j] += __shfl_xor(ap[j], o);
    if (lane == 0) {
        for (int hh = 0; hh < 4; ++hh) {
            as_[nd * 4 + hh] = ap[hh];
            ad_[nd * 4 + hh] = ap[4 + hh];
        }
    }

    // fp8 table write (perm layout): storage s = lane*8 + t holds logical channel c = t*16 + lane
    float pv[8];
    for (int t = 0; t < 8; ++t) {
        int c = t * 16 + (lane & 15);
        float s1 = __shfl(va, c & 63);
        float s2 = __shfl(vb, c & 63);
        pv[t] = (c < 64) ? s1 : s2;
    }
    if (lane < 16) {
        int w0 = __builtin_amdgcn_cvt_pk_fp8_f32(pv[0], pv[1], 0, false);
        w0     = __builtin_amdgcn_cvt_pk_fp8_f32(pv[2], pv[3], w0, true);
        int w1 = __builtin_amdgcn_cvt_pk_fp8_f32(pv[4], pv[5], 0, false);
        w1     = __builtin_amdgcn_cvt_pk_fp8_f32(pv[6], pv[7], w1, true);
        *(int2*)(ln8 + base + lane * 8) = make_int2(w0, w1);
    }
}

// ---------------- fused edge-softmax + per-node aggregate ----------------
// 1 wave per node; 4 lane-groups of 16.  Per 64-edge chunk:
//   phase A: lane e computes p[e][4] = exp(lrelu(as[src]+ad[nd])) -> LDS (src stays in reg)
//   phase B: group g takes edge 4i+g; lane l gathers 8 fp8 channels (s = l*8..l*8+7) = 8B/lane
// Epilogue: xor(32)/xor(16) cross-group reduce, normalize, group g stores head g's
// A-frag octet: agg[((tile*16 + g*4 + (l>>2))*64 + (l&3)*16 + m)*8 + j], j=0..7.

__device__ inline f32x2 shx2(f32x2 v, int m) {
    f32x2 r; r[0] = __shfl_xor(v[0], m); r[1] = __shfl_xor(v[1], m); return r;
}

__global__ __launch_bounds__(256) void k_agg(const unsigned char* __restrict__ ln8,
                                             const int* __restrict__ row_ptr,
                                             const int* __restrict__ csr_src,
                                             const float* __restrict__ as_,
                                             const float* __restrict__ ad_,
                                             _Float16* __restrict__ agg) {
    __shared__ float psm[4][64][4];     // 4 KB: per-wave p staging
    int tid = threadIdx.x;
    int lane = tid & 63;
    int w = tid >> 6;
    int g = lane >> 4;
    int l = lane & 15;
    int nd = blockIdx.x * 4 + w;

    int e0 = row_ptr[nd], e1 = row_ptr[nd + 1];
    float4 ad4 = *(const float4*)(ad_ + (size_t)nd * 4);

    f32x2 a00 = (f32x2)(0.f), a01 = (f32x2)(0.f), a02 = (f32x2)(0.f), a03 = (f32x2)(0.f);
    f32x2 a10 = (f32x2)(0.f), a11 = (f32x2)(0.f), a12 = (f32x2)(0.f), a13 = (f32x2)(0.f);
    f32x2 a20 = (f32x2)(0.f), a21 = (f32x2)(0.f), a22 = (f32x2)(0.f), a23 = (f32x2)(0.f);
    f32x2 a30 = (f32x2)(0.f), a31 = (f32x2)(0.f), a32 = (f32x2)(0.f), a33 = (f32x2)(0.f);
    float z0 = 0.f, z1 = 0.f, z2 = 0.f, z3 = 0.f;

    const unsigned char* xb = ln8 + l * 8;
    float* pb = &psm[w][0][0];

    for (int cs = e0; cs < e1; cs += 64) {
        int nA = min(64, e1 - cs);
        // prior chunk's phase-B LDS reads must complete before overwrite (multi-chunk only)
        asm volatile("s_waitcnt lgkmcnt(0)" ::: "memory");
        // ---- phase A: per-edge p into LDS ----
        int srcA = nd;
        float4 pv = make_float4(0.f, 0.f, 0.f, 0.f);
        if (lane < nA) {
            srcA = csr_src[cs + lane];
            float4 a4 = *(const float4*)(as_ + (size_t)srcA * 4);
            float t;
            t = a4.x + ad4.x; t = (t >= 0.f) ? t : NEG_SLOPE * t; pv.x = __expf(t);
            t = a4.y + ad4.y; t = (t >= 0.f) ? t : NEG_SLOPE * t; pv.y = __expf(t);
            t = a4.z + ad4.z; t = (t >= 0.f) ? t : NEG_SLOPE * t; pv.z = __expf(t);
            t = a4.w + ad4.w; t = (t >= 0.f) ? t : NEG_SLOPE * t; pv.w = __expf(t);
        }
        *(float4*)(pb + lane * 4) = pv;
        asm volatile("s_waitcnt lgkmcnt(0)" ::: "memory");
        __builtin_amdgcn_sched_barrier(0);

        // ---- phase B: group g takes edge 4i+g, 8 channels/lane ----
        int iters = (nA + 3) >> 2;
        for (int i = 0; i < iters; ++i) {
            int idx = i * 4 + g;                       // <= 63 always
            float4 p4 = *(const float4*)(pb + idx * 4);  // group-uniform; 0 for pad slots
            int sidx = __shfl(srcA, idx);
            int2 xw = *(const int2*)(xb + (size_t)sidx * 128);
            f32x2 v0 = __builtin_amdgcn_cvt_pk_f32_fp8(xw.x, false);
            f32x2 v1 = __builtin_amdgcn_cvt_pk_f32_fp8(xw.x, true);
            f32x2 v2 = __builtin_amdgcn_cvt_pk_f32_fp8(xw.y, false);
            f32x2 v3 = __builtin_amdgcn_cvt_pk_f32_fp8(xw.y, true);
            a00 += (f32x2)(p4.x) * v0; a01 += (f32x2)(p4.x) * v1;
            a02 += (f32x2)(p4.x) * v2; a03 += (f32x2)(p4.x) * v3;
            a10 += (f32x2)(p4.y) * v0; a11 += (f32x2)(p4.y) * v1;
            a12 += (f32x2)(p4.y) * v2; a13 += (f32x2)(p4.y) * v3;
            a20 += (f32x2)(p4.z) * v0; a21 += (f32x2)(p4.z) * v1;
            a22 += (f32x2)(p4.z) * v2; a23 += (f32x2)(p4.z) * v3;
            a30 += (f32x2)(p4.w) * v0; a31 += (f32x2)(p4.w) * v1;
            a32 += (f32x2)(p4.w) * v2; a33 += (f32x2)(p4.w) * v3;
            z0 += p4.x; z1 += p4.y; z2 += p4.z; z3 += p4.w;
        }
    }

    // ---- cross-group reduce (lanes l fixed; xor32 flips g-bit1, xor16 flips g-bit0) ----
#define RED2(v) v += shx2(v, 32); v += shx2(v, 16)
    RED2(a00); RED2(a01); RED2(a02); RED2(a03);
    RED2(a10); RED2(a11); RED2(a12); RED2(a13);
    RED2(a20); RED2(a21); RED2(a22); RED2(a23);
    RED2(a30); RED2(a31); RED2(a32); RED2(a33);
#undef RED2
    z0 += __shfl_xor(z0, 32); z0 += __shfl_xor(z0, 16);
    z1 += __shfl_xor(z1, 32); z1 += __shfl_xor(z1, 16);
    z2 += __shfl_xor(z2, 32); z2 += __shfl_xor(z2, 16);
    z3 += __shfl_xor(z3, 32); z3 += __shfl_xor(z3, 16);

    // ---- group g writes head g ----
    f32x2 s0, s1, s2, s3;
    float zz;
    if (g == 0)      { s0 = a00; s1 = a01; s2 = a02; s3 = a03; zz = z0; }
    else if (g == 1) { s0 = a10; s1 = a11; s2 = a12; s3 = a13; zz = z1; }
    else if (g == 2) { s0 = a20; s1 = a21; s2 = a22; s3 = a23; zz = z2; }
    else             { s0 = a30; s1 = a31; s2 = a32; s3 = a33; zz = z3; }
    f32x2 inv = (f32x2)(1.0f / zz);
    s0 *= inv; s1 *= inv; s2 *= inv; s3 *= inv;

    union { _Float16 hx[8]; int4 v4; } cf;
    cf.hx[0] = (_Float16)s0[0]; cf.hx[1] = (_Float16)s0[1];
    cf.hx[2] = (_Float16)s1[0]; cf.hx[3] = (_Float16)s1[1];
    cf.hx[4] = (_Float16)s2[0]; cf.hx[5] = (_Float16)s2[1];
    cf.hx[6] = (_Float16)s3[0]; cf.hx[7] = (_Float16)s3[1];

    int tile = nd >> 4, m = nd & 15;
    _Float16* dst = agg + (((size_t)tile * 16 + g * 4 + (l >> 2)) * 64 + (l & 3) * 16 + m) * 8;
    *(int4*)dst = cf.v4;
}

// ---------------- gemm2: agg(frag) x B''(LDS-staged) -> epilogue -> h, ln8, alphas ----------------

__global__ __launch_bounds__(256) void k_gemm2(const _Float16* __restrict__ agg,
                                               const _Float16* __restrict__ Bp,
                                               const float* __restrict__ ws,
                                               const float* __restrict__ bias,
                                               const float* __restrict__ gamma,
                                               const float* __restrict__ beta,
                                               float* __restrict__ h,
                                               unsigned char* __restrict__ ln8,
                                               float* __restrict__ as_,
                                               float* __restrict__ ad_,
                                               _Float16* __restrict__ h16,
                                               int write_ln, int last) {
    __shared__ _Float16 Bs[4096];       // 8 KB: [nt(8)][lane(64)][j(8)]
    int tid = threadIdx.x;
    int lane = tid & 63;
    int w = tid >> 6;
    int tile = blockIdx.x * 4 + w;
    int valid = (tile < NT2);
    if (!valid) tile = 0;               // stay for barriers; all global writes guarded
    int quad = lane >> 4;
    int l15  = lane & 15;

    int ntS  = tid >> 5;
    int remS = (tid & 31) * 16;

    f32x4 acc[8];
    for (int nt = 0; nt < 8; ++nt) acc[nt] = (f32x4)(0.0f);

    const _Float16* abase = agg + (size_t)tile * 8192 + lane * 8;
    for (int kc = 0; kc < 16; ++kc) {
        half8 a = *(const half8*)(abase + kc * 512);
        const _Float16* src = Bp + ((size_t)(ntS * 16 + kc)) * 512 + remS;
        __syncthreads();
        *(half8*)(Bs + tid * 16)     = *(const half8*)(src);
        *(half8*)(Bs + tid * 16 + 8) = *(const half8*)(src + 8);
        __syncthreads();
        for (int nt = 0; nt < 8; ++nt) {
            half8 b = *(const half8*)(Bs + nt * 512 + lane * 8);
            acc[nt] = __builtin_amdgcn_mfma_f32_16x16x32_f16(a, b, acc[nt], 0, 0, 0);
        }
    }

    if (!valid) return;

    int row0 = tile * 16;
    float bi[8];
    for (int nt = 0; nt < 8; ++nt) bi[nt] = bias[nt * 16 + l15];
    float ga[8], be[8], wsv[8][8];
    if (write_ln) {
        for (int nt = 0; nt < 8; ++nt) {
            int c = nt * 16 + l15;
            ga[nt] = gamma[c];
            be[nt] = beta[c];
            for (int j = 0; j < 8; ++j) wsv[nt][j] = ws[c * 8 + j];
        }
    }

    for (int r = 0; r < 4; ++r) {
        int node = row0 + quad * 4 + r;
        float* hr = h + (size_t)node * HID;
        float rv[8];
        for (int nt = 0; nt < 8; ++nt) {
            float t = acc[nt][r] + bi[nt];
            t = fmaxf(t, 0.f);
            rv[nt] = t + hr[nt * 16 + l15];
        }
        if (!last) {
            for (int nt = 0; nt < 8; ++nt) hr[nt * 16 + l15] = rv[nt];
        } else {
            union { _Float16 hx[8]; int4 v4; } cf;
            for (int nt = 0; nt < 8; ++nt) cf.hx[nt] = (_Float16)rv[nt];
            int kc = l15 >> 2;
            int lf = (l15 & 3) * 16 + quad * 4 + r;
            *(int4*)(h16 + (((size_t)tile * 4 + kc) * 64 + lf) * 8) = cf.v4;
        }

        if (write_ln) {
            float s = 0.f;
            for (int nt = 0; nt < 8; ++nt) s += rv[nt];
            s += __shfl_xor(s, 1); s += __shfl_xor(s, 2);
            s += __shfl_xor(s, 4); s += __shfl_xor(s, 8);
            float mu = s * (1.0f / 128.0f);
            float var = 0.f;
            for (int nt = 0; nt < 8; ++nt) { float d = rv[nt] - mu; var += d * d; }
            var += __shfl_xor(var, 1); var += __shfl_xor(var, 2);
            var += __shfl_xor(var, 4); var += __shfl_xor(var, 8);
            float rstd = rsqrtf(var * (1.0f / 128.0f) + LN_EPS);
            float lnv[8];
            for (int nt = 0; nt < 8; ++nt)
                lnv[nt] = (rv[nt] - mu) * rstd * ga[nt] + be[nt];

            float ap[8];
            for (int j = 0; j < 8; ++j) {
                float t = 0.f;
                for (int nt = 0; nt < 8; ++nt) t += lnv[nt] * wsv[nt][j];
                ap[j] = t;
            }
            for (int j = 0; j < 8; ++j) {
                ap[j] += __shfl_xor(ap[j], 1); ap[j] += __shfl_xor(ap[j], 2);
                ap[j] += __shfl_xor(ap[j], 4); ap[j] += __shfl_xor(ap[j], 8);
            }
            if (l15 == 0) {
                for (int hh = 0; hh < 4; ++hh) {
                    as_[node * 4 + hh] = ap[hh];
                    ad_[node * 4 + hh] = ap[4 + hh];
                }
            }

            int w0 = __builtin_amdgcn_cvt_pk_fp8_f32(lnv[0], lnv[1], 0, false);
            w0     = __builtin_amdgcn_cvt_pk_fp8_f32(lnv[2], lnv[3], w0, true);
            int w1 = __builtin_amdgcn_cvt_pk_fp8_f32(lnv[4], lnv[5], 0, false);
            w1     = __builtin_amdgcn_cvt_pk_fp8_f32(lnv[6], lnv[7], w1, true);
            *(int2*)(ln8 + (size_t)node * 128 + l15 * 8) = make_int2(w0, w1);
        }
    }
}

// ---------------- output projection: fp16 MFMA streaming GEMM ----------------

__global__ __launch_bounds__(256) void k_out_proj_mfma(const _Float16* __restrict__ h16,
                                                       const _Float16* __restrict__ Bout,
                                                       const float* __restrict__ b,
                                                       float* __restrict__ out) {
    int tid = threadIdx.x;
    int lane = tid & 63;
    int tile = blockIdx.x * 4 + (tid >> 6);
    if (tile >= NT2) return;

    const _Float16* ab = h16 + (size_t)tile * 2048 + lane * 8;
    f32x4 acc[4];
    for (int nt = 0; nt < 4; ++nt) acc[nt] = (f32x4)(0.0f);
    #pragma unroll
    for (int kc = 0; kc < 4; ++kc) {
        half8 a = *(const half8*)(ab + kc * 512);
        #pragma unroll
        for (int nt = 0; nt < 4; ++nt) {
            half8 bf = *(const half8*)(Bout + ((size_t)(kc * 4 + nt) * 64 + lane) * 8);
            acc[nt] = __builtin_amdgcn_mfma_f32_16x16x32_f16(a, bf, acc[nt], 0, 0, 0);
        }
    }

    int l15 = lane & 15, quad = lane >> 4;
    float bo[4];
    #pragma unroll
    for (int nt = 0; nt < 4; ++nt) bo[nt] = b[nt * 16 + l15];
    #pragma unroll
    for (int r = 0; r < 4; ++r) {
        int node = tile * 16 + quad * 4 + r;
        float* orow = out + (size_t)node * OUTC;
        #pragma unroll
        for (int nt = 0; nt < 4; ++nt)
            orow[nt * 16 + l15] = acc[nt][r] + bo[nt];
    }
}

// ---------------- launch ----------------

extern "C" void kernel_launch(void* const* d_in, const int* in_sizes, int n_in,
                              void* d_out, int out_size, void* d_ws, size_t ws_size,
                              hipStream_t stream) {
    const float* x       = (const float*)d_in[0];
    const int*   ei      = (const int*)d_in[1];
    const float* W_in    = (const float*)d_in[2];
    const float* b_in    = (const float*)d_in[3];
    const float* W_conv  = (const float*)d_in[4];
    const float* att_src = (const float*)d_in[5];
    const float* att_dst = (const float*)d_in[6];
    const float* b_conv  = (const float*)d_in[7];
    const float* ln_g    = (const float*)d_in[8];
    const float* ln_b    = (const float*)d_in[9];
    const float* W_out   = (const float*)d_in[10];
    const float* b_out   = (const float*)d_in[11];
    float* out = (float*)d_out;

    char* ws = (char*)d_ws;
    size_t off = 0;
    auto alloc = [&](size_t bytes) { void* p = ws + off; off = (off + bytes + 255) & ~(size_t)255; return p; };
    float* h            = (float*)alloc((size_t)N_NODES * HID * 4);
    _Float16* agg       = (_Float16*)alloc((size_t)NT2 * 8192 * 2);   // frag layout
    unsigned char* ln8  = (unsigned char*)alloc((size_t)N_NODES * 128);
    float* as_          = (float*)alloc((size_t)N_NODES * 4 * 4);
    float* ad_          = (float*)alloc((size_t)N_NODES * 4 * 4);
    _Float16* Bp2       = (_Float16*)alloc((size_t)DEPTH * 65536 * 2);
    float* ws_all       = (float*)alloc((size_t)DEPTH * 1024 * 4);
    _Float16* h16       = (_Float16*)alloc((size_t)NT2 * 2048 * 2);   // out-proj A-frags
    _Float16* Bout      = (_Float16*)alloc((size_t)8192 * 2);         // out-proj B-frags
    int* deg    = (int*)alloc((size_t)N_NODES * 4);
    int* cur    = (int*)alloc((size_t)N_NODES * 4);
    int* row_ptr= (int*)alloc((size_t)(N_NODES + 1) * 4);
    int* csr    = (int*)alloc((size_t)E2 * 4);
    int* bsum   = (int*)alloc(256 * 4);
    (void)ws_size; (void)n_in; (void)in_sizes; (void)out_size;

    hipMemsetAsync(deg, 0, (size_t)N_NODES * 4, stream);
    hipMemsetAsync(cur, 0, (size_t)N_NODES * 4, stream);

    // CSR build
    k_deg<<<(E2 + 255) / 256, 256, 0, stream>>>(ei, deg);
    int nb = (N_NODES + 1023) / 1024;
    k_scan_block<<<nb, 1024, 0, stream>>>(deg, row_ptr, bsum, N_NODES);
    k_scan_bsum<<<1, 64, 0, stream>>>(bsum, nb);
    k_scan_fix<<<nb, 1024, 0, stream>>>(deg, row_ptr, bsum, N_NODES);
    k_fill<<<(E2 + 255) / 256, 256, 0, stream>>>(ei, row_ptr, cur, csr);

    // weight preprocessing (per call; graph-safe)
    k_ws<<<(DEPTH * 1024 + 255) / 256, 256, 0, stream>>>(W_conv, att_src, att_dst, ws_all);
    k_repackB2<<<(DEPTH * 65536 + 255) / 256, 256, 0, stream>>>(W_conv, Bp2);
    k_repackBout<<<32, 256, 0, stream>>>(W_out, Bout);

    // input projection + first LN (fp8 table + layer-0 alphas)
    k_in_proj_ln<<<N_NODES / 4, 256, 0, stream>>>(x, W_in, b_in, ln_g, ln_b, ws_all,
                                                  h, ln8, as_, ad_);

    // layers (k_edge fused into k_agg)
    for (int i = 0; i < DEPTH; ++i) {
        const float* bcp = b_conv + (size_t)i * HID;
        int write_ln = (i + 1 < DEPTH) ? 1 : 0;
        int last = (i + 1 == DEPTH) ? 1 : 0;
        int nl = (i + 1 < DEPTH) ? i + 1 : i;
        const float* gp = ln_g + (size_t)nl * HID;
        const float* bp = ln_b + (size_t)nl * HID;
        const float* wsp = ws_all + (size_t)nl * 1024;

        k_agg<<<N_NODES / 4, 256, 0, stream>>>(ln8, row_ptr, csr, as_, ad_, agg);
        k_gemm2<<<(NT2 + 3) / 4, 256, 0, stream>>>(agg, Bp2 + (size_t)i * 65536, wsp,
                                                   bcp, gp, bp, h, ln8, as_, ad_,
                                                   h16, write_ln, last);
    }

    k_out_proj_mfma<<<(NT2 + 3) / 4, 256, 0, stream>>>(h16, Bout, b_out, out);
}

// Round 3
// 463.461 us; speedup vs baseline: 1.3945x; 1.3340x over previous
//
#include <hip/hip_runtime.h>
#include <hip/hip_fp16.h>
#include <math.h>

#define N_NODES 50000
#define E_EDGES 800000
#define E2 (E_EDGES + N_NODES)
#define HID 128
#define HEADS 4
#define OUTC 64
#define DEPTH 4
#define NEG_SLOPE 0.2f
#define LN_EPS 1e-6f
#define NT2 3125          // 16-row tiles (50000/16 exactly)

typedef float f32x4 __attribute__((ext_vector_type(4)));
typedef float f32x2 __attribute__((ext_vector_type(2)));
typedef _Float16 half8 __attribute__((ext_vector_type(8)));

// ---------------- CSR build ----------------

__global__ void k_deg(const int* __restrict__ ei, int* __restrict__ deg) {
    int e = blockIdx.x * 256 + threadIdx.x;
    if (e >= E2) return;
    int d = (e < E_EDGES) ? ei[E_EDGES + e] : (e - E_EDGES);
    atomicAdd(&deg[d], 1);
}

__global__ void k_scan_block(const int* __restrict__ deg, int* __restrict__ partial,
                             int* __restrict__ bsum, int n) {
    __shared__ int sm[1024];
    int i = blockIdx.x * 1024 + threadIdx.x;
    int v = (i < n) ? deg[i] : 0;
    sm[threadIdx.x] = v;
    __syncthreads();
    for (int off = 1; off < 1024; off <<= 1) {
        int t = (threadIdx.x >= off) ? sm[threadIdx.x - off] : 0;
        __syncthreads();
        sm[threadIdx.x] += t;
        __syncthreads();
    }
    if (i < n) partial[i] = sm[threadIdx.x];
    if (threadIdx.x == 1023) bsum[blockIdx.x] = sm[1023];
}

__global__ void k_scan_bsum(int* __restrict__ bsum, int nb) {
    if (threadIdx.x == 0 && blockIdx.x == 0) {
        int run = 0;
        for (int b = 0; b < nb; ++b) { int v = bsum[b]; bsum[b] = run; run += v; }
    }
}

__global__ void k_scan_fix(const int* __restrict__ deg, int* __restrict__ row_ptr,
                           const int* __restrict__ bsum, int n) {
    int i = blockIdx.x * 1024 + threadIdx.x;
    if (i < n) row_ptr[i] = row_ptr[i] - deg[i] + bsum[blockIdx.x];
    if (i == 0) row_ptr[n] = E2;
}

__global__ void k_fill(const int* __restrict__ ei, const int* __restrict__ row_ptr,
                       int* __restrict__ cur, int* __restrict__ csr_src) {
    int e = blockIdx.x * 256 + threadIdx.x;
    if (e >= E2) return;
    int s, d;
    if (e < E_EDGES) { s = ei[e]; d = ei[E_EDGES + e]; } else { s = d = e - E_EDGES; }
    int pos = atomicAdd(&cur[d], 1);
    csr_src[row_ptr[d] + pos] = s;
}

// ---------------- ws[layer][c][j]: fused attention weights: ws = W . att ----------------

__global__ void k_ws(const float* __restrict__ W_conv, const float* __restrict__ att_s,
                     const float* __restrict__ att_d, float* __restrict__ ws_all) {
    int idx = blockIdx.x * 256 + threadIdx.x;
    if (idx >= DEPTH * 1024) return;
    int j = idx & 7, c = (idx >> 3) & 127, layer = idx >> 10;
    int hh = j & 3, sd = j >> 2;
    const float* Wr = W_conv + (size_t)layer * 65536 + (size_t)c * 512 + hh * HID;
    const float* at = (sd ? att_d : att_s) + (size_t)layer * HEADS * HID + hh * HID;
    float s = 0.f;
    for (int cc = 0; cc < HID; ++cc) s += Wr[cc] * at[cc];
    ws_all[idx] = s;
}

// ---------------- repack W_conv into gemm B-frags: B''[k=h*128+s][n] = W[c(s), h*128+n]/4 ----
// storage perm: s = l15*8 + nt  ->  logical channel c = (s&7)*16 + (s>>3)

__global__ void k_repackB2(const float* __restrict__ W_conv, _Float16* __restrict__ Bp) {
    int idx = blockIdx.x * 256 + threadIdx.x;
    if (idx >= DEPTH * 65536) return;
    int jj    = idx & 7;
    int lane  = (idx >> 3) & 63;
    int kc    = (idx >> 9) & 15;
    int ntile = (idx >> 13) & 7;
    int layer = idx >> 16;
    int k = kc * 32 + (lane >> 4) * 8 + jj;
    int n = ntile * 16 + (lane & 15);
    int hh = k >> 7;
    int s  = k & 127;
    int c  = (s & 7) * 16 + (s >> 3);
    Bp[idx] = (_Float16)(0.25f * W_conv[(size_t)layer * 65536 + (size_t)c * 512 + hh * HID + n]);
}

// ---------------- repack W_out into out-proj B-frags (same channel perm, fp16) -----------

__global__ void k_repackBout(const float* __restrict__ W_out, _Float16* __restrict__ Bout) {
    int idx = blockIdx.x * 256 + threadIdx.x;
    if (idx >= 8192) return;
    int j    = idx & 7;
    int lane = (idx >> 3) & 63;
    int nt   = (idx >> 9) & 3;
    int kc   = idx >> 11;
    int k = kc * 32 + (lane >> 4) * 8 + j;
    int c = (k & 7) * 16 + (k >> 3);
    int n = nt * 16 + (lane & 15);
    Bout[idx] = (_Float16)W_out[(size_t)c * OUTC + n];
}

// ---------------- input projection + LN -> fp8 ln table (perm layout) + layer-0 alphas ----------------

__global__ __launch_bounds__(256) void k_in_proj_ln(const float* __restrict__ x,
                                                    const float* __restrict__ W,
                                                    const float* __restrict__ bias,
                                                    const float* __restrict__ gamma,
                                                    const float* __restrict__ beta,
                                                    const float* __restrict__ ws,
                                                    float* __restrict__ h,
                                                    unsigned char* __restrict__ ln8,
                                                    float* __restrict__ as_,
                                                    float* __restrict__ ad_) {
    int tid = threadIdx.x;
    int lane = tid & 63;
    int nd = blockIdx.x * 4 + (tid >> 6);
    const float* xr = x + nd * 3;
    float x0 = xr[0], x1 = xr[1], x2 = xr[2];
    int j0 = lane, j1 = lane + 64;
    float a = bias[j0] + x0 * W[j0] + x1 * W[HID + j0] + x2 * W[2 * HID + j0];
    float b = bias[j1] + x0 * W[j1] + x1 * W[HID + j1] + x2 * W[2 * HID + j1];
    size_t base = (size_t)nd * HID;
    h[base + j0] = a;
    h[base + j1] = b;
    float s = a + b;
    for (int o = 1; o < 64; o <<= 1) s += __shfl_xor(s, o);
    float mu = s * (1.0f / 128.0f);
    float da = a - mu, db = b - mu;
    float v = da * da + db * db;
    for (int o = 1; o < 64; o <<= 1) v += __shfl_xor(v, o);
    float rstd = rsqrtf(v * (1.0f / 128.0f) + LN_EPS);
    float va = da * rstd * gamma[j0] + beta[j0];
    float vb = db * rstd * gamma[j1] + beta[j1];

    // layer-0 alphas
    float ap[8];
    for (int j = 0; j < 8; ++j)
        ap[j] = va * ws[j0 * 8 + j] + vb * ws[j1 * 8 + j];
    for (int o = 1; o < 64; o <<= 1)
        for (int j = 0; j < 8; ++j) ap[j] += __shfl_xor(ap[j], o);
    if (lane == 0) {
        for (int hh = 0; hh < 4; ++hh) {
            as_[nd * 4 + hh] = ap[hh];
            ad_[nd * 4 + hh] = ap[4 + hh];
        }
    }

    // fp8 table write (perm layout): storage s = lane*8 + t holds logical channel c = t*16 + lane
    float pv[8];
    for (int t = 0; t < 8; ++t) {
        int c = t * 16 + (lane & 15);
        float s1 = __shfl(va, c & 63);
        float s2 = __shfl(vb, c & 63);
        pv[t] = (c < 64) ? s1 : s2;
    }
    if (lane < 16) {
        int w0 = __builtin_amdgcn_cvt_pk_fp8_f32(pv[0], pv[1], 0, false);
        w0     = __builtin_amdgcn_cvt_pk_fp8_f32(pv[2], pv[3], w0, true);
        int w1 = __builtin_amdgcn_cvt_pk_fp8_f32(pv[4], pv[5], 0, false);
        w1     = __builtin_amdgcn_cvt_pk_fp8_f32(pv[6], pv[7], w1, true);
        *(int2*)(ln8 + base + lane * 8) = make_int2(w0, w1);
    }
}

// ---------------- fused layer: edge-softmax + aggregate (LDS frags) + MFMA gemm + epilogue ----
// Block = one 16-node tile, 4 waves.  Group (16 lanes) per node: lane l owns storage
// bytes l*8..l*8+7 of the perm'd LN row, all 4 heads (16 f32x2 accumulators); p computed
// redundantly in-group (no cross-lane ops, no LDS ping-pong).  A-frags -> LDS (16 KB),
// then wave w computes column-blocks {2w, 2w+1} via MFMA (B frags L2-hot), C -> padded
// LDS tile, then per-row LN/alpha/fp8 epilogue (row = quad*4 + w).
// ln8/as_/ad_ are ping-pong (read cur layer, write next) to avoid inter-block races.

__global__ __launch_bounds__(256) void k_layer(const unsigned char* __restrict__ ln8r,
                                               const int* __restrict__ row_ptr,
                                               const int* __restrict__ csr_src,
                                               const float* __restrict__ asr,
                                               const float* __restrict__ adr,
                                               const _Float16* __restrict__ Bp,
                                               const float* __restrict__ ws,
                                               const float* __restrict__ bias,
                                               const float* __restrict__ gamma,
                                               const float* __restrict__ beta,
                                               float* __restrict__ h,
                                               unsigned char* __restrict__ ln8w,
                                               float* __restrict__ asw,
                                               float* __restrict__ adw,
                                               _Float16* __restrict__ h16,
                                               int write_ln, int last) {
    __shared__ _Float16 Afr[8192];      // 16 KB A-frags: [kc(16)][lane(64)][j(8)]
    __shared__ float Cts[16][132];      // 8.25 KB padded C tile [row][col]
    int tid  = threadIdx.x;
    int lane = tid & 63;
    int w    = tid >> 6;
    int g    = lane >> 4;
    int l    = lane & 15;
    int quad = lane >> 4;
    int l15  = lane & 15;
    int tile = blockIdx.x;
    int m    = w * 4 + g;
    int nd   = tile * 16 + m;

    // ---- aggregation ----
    int e0 = row_ptr[nd], e1 = row_ptr[nd + 1];
    float4 ad4 = *(const float4*)(adr + (size_t)nd * 4);

    f32x2 a00 = (f32x2)(0.f), a01 = (f32x2)(0.f), a02 = (f32x2)(0.f), a03 = (f32x2)(0.f);
    f32x2 a10 = (f32x2)(0.f), a11 = (f32x2)(0.f), a12 = (f32x2)(0.f), a13 = (f32x2)(0.f);
    f32x2 a20 = (f32x2)(0.f), a21 = (f32x2)(0.f), a22 = (f32x2)(0.f), a23 = (f32x2)(0.f);
    f32x2 a30 = (f32x2)(0.f), a31 = (f32x2)(0.f), a32 = (f32x2)(0.f), a33 = (f32x2)(0.f);
    float4 zz = make_float4(0.f, 0.f, 0.f, 0.f);

    const unsigned char* xb = ln8r + l * 8;

#define EDGE_P(Q, P) do {                                                   \
    float t_;                                                               \
    t_ = (Q).x + ad4.x; t_ = (t_ >= 0.f) ? t_ : NEG_SLOPE * t_; (P).x = __expf(t_); \
    t_ = (Q).y + ad4.y; t_ = (t_ >= 0.f) ? t_ : NEG_SLOPE * t_; (P).y = __expf(t_); \
    t_ = (Q).z + ad4.z; t_ = (t_ >= 0.f) ? t_ : NEG_SLOPE * t_; (P).z = __expf(t_); \
    t_ = (Q).w + ad4.w; t_ = (t_ >= 0.f) ? t_ : NEG_SLOPE * t_; (P).w = __expf(t_); \
} while (0)

#define ACC_EDGE(P, X) do {                                                 \
    f32x2 v0 = __builtin_amdgcn_cvt_pk_f32_fp8((X).x, false);               \
    f32x2 v1 = __builtin_amdgcn_cvt_pk_f32_fp8((X).x, true);                \
    f32x2 v2 = __builtin_amdgcn_cvt_pk_f32_fp8((X).y, false);               \
    f32x2 v3 = __builtin_amdgcn_cvt_pk_f32_fp8((X).y, true);                \
    a00 += (f32x2)((P).x) * v0; a01 += (f32x2)((P).x) * v1;                 \
    a02 += (f32x2)((P).x) * v2; a03 += (f32x2)((P).x) * v3;                 \
    a10 += (f32x2)((P).y) * v0; a11 += (f32x2)((P).y) * v1;                 \
    a12 += (f32x2)((P).y) * v2; a13 += (f32x2)((P).y) * v3;                 \
    a20 += (f32x2)((P).z) * v0; a21 += (f32x2)((P).z) * v1;                 \
    a22 += (f32x2)((P).z) * v2; a23 += (f32x2)((P).z) * v3;                 \
    a30 += (f32x2)((P).w) * v0; a31 += (f32x2)((P).w) * v1;                 \
    a32 += (f32x2)((P).w) * v2; a33 += (f32x2)((P).w) * v3;                 \
    zz.x += (P).x; zz.y += (P).y; zz.z += (P).z; zz.w += (P).w;             \
} while (0)

    int e = e0;
    for (; e + 2 <= e1; e += 2) {
        int s0 = csr_src[e];
        int s1 = csr_src[e + 1];
        float4 q0 = *(const float4*)(asr + (size_t)s0 * 4);
        float4 q1 = *(const float4*)(asr + (size_t)s1 * 4);
        int2 x0 = *(const int2*)(xb + (size_t)s0 * 128);
        int2 x1 = *(const int2*)(xb + (size_t)s1 * 128);
        float4 p0, p1;
        EDGE_P(q0, p0);
        EDGE_P(q1, p1);
        ACC_EDGE(p0, x0);
        ACC_EDGE(p1, x1);
    }
    if (e < e1) {
        int s0 = csr_src[e];
        float4 q0 = *(const float4*)(asr + (size_t)s0 * 4);
        int2 x0 = *(const int2*)(xb + (size_t)s0 * 128);
        float4 p0;
        EDGE_P(q0, p0);
        ACC_EDGE(p0, x0);
    }
#undef EDGE_P
#undef ACC_EDGE

    // normalize and pack A-frags into LDS: head h -> kc = h*4 + (l>>2), fraglane = (l&3)*16 + m
    {
        f32x2 i0 = (f32x2)(1.0f / zz.x), i1 = (f32x2)(1.0f / zz.y);
        f32x2 i2 = (f32x2)(1.0f / zz.z), i3 = (f32x2)(1.0f / zz.w);
        a00 *= i0; a01 *= i0; a02 *= i0; a03 *= i0;
        a10 *= i1; a11 *= i1; a12 *= i1; a13 *= i1;
        a20 *= i2; a21 *= i2; a22 *= i2; a23 *= i2;
        a30 *= i3; a31 *= i3; a32 *= i3; a33 *= i3;
        int fl = (l & 3) * 16 + m;
        int kb = l >> 2;
        union { _Float16 hx[8]; int4 v4; } cf;
#define STORE_HEAD(H, P0, P1, P2, P3) do {                                  \
        cf.hx[0] = (_Float16)P0[0]; cf.hx[1] = (_Float16)P0[1];             \
        cf.hx[2] = (_Float16)P1[0]; cf.hx[3] = (_Float16)P1[1];             \
        cf.hx[4] = (_Float16)P2[0]; cf.hx[5] = (_Float16)P2[1];             \
        cf.hx[6] = (_Float16)P3[0]; cf.hx[7] = (_Float16)P3[1];             \
        *(int4*)(Afr + ((((H) * 4 + kb) * 64 + fl) * 8)) = cf.v4;           \
} while (0)
        STORE_HEAD(0, a00, a01, a02, a03);
        STORE_HEAD(1, a10, a11, a12, a13);
        STORE_HEAD(2, a20, a21, a22, a23);
        STORE_HEAD(3, a30, a31, a32, a33);
#undef STORE_HEAD
    }
    __syncthreads();

    // ---- MFMA gemm: wave w -> column-blocks nt0 = 2w, nt1 = 2w+1 ----
    {
        int nt0 = w * 2, nt1 = w * 2 + 1;
        f32x4 c0 = (f32x4)(0.f), c1 = (f32x4)(0.f);
        const _Float16* b0p = Bp + (size_t)nt0 * 8192 + lane * 8;
        const _Float16* b1p = Bp + (size_t)nt1 * 8192 + lane * 8;
        #pragma unroll
        for (int kc = 0; kc < 16; ++kc) {
            half8 a  = *(const half8*)(Afr + (kc * 64 + lane) * 8);
            half8 b0 = *(const half8*)(b0p + kc * 512);
            half8 b1 = *(const half8*)(b1p + kc * 512);
            c0 = __builtin_amdgcn_mfma_f32_16x16x32_f16(a, b0, c0, 0, 0, 0);
            c1 = __builtin_amdgcn_mfma_f32_16x16x32_f16(a, b1, c1, 0, 0, 0);
        }
        #pragma unroll
        for (int r = 0; r < 4; ++r) {
            Cts[quad * 4 + r][nt0 * 16 + l15] = c0[r];
            Cts[quad * 4 + r][nt1 * 16 + l15] = c1[r];
        }
    }
    __syncthreads();

    // ---- epilogue: row = quad*4 + w (16-lane group per row) ----
    int row = quad * 4 + w;
    int node = tile * 16 + row;
    float* hr = h + (size_t)node * HID;

    float rv[8];
    #pragma unroll
    for (int nt = 0; nt < 8; ++nt) {
        float t = Cts[row][nt * 16 + l15] + bias[nt * 16 + l15];
        t = fmaxf(t, 0.f);
        rv[nt] = t + hr[nt * 16 + l15];
    }
    if (!last) {
        #pragma unroll
        for (int nt = 0; nt < 8; ++nt) hr[nt * 16 + l15] = rv[nt];
    } else {
        // fp16 A-frag emit for out-proj: k = l15*8 + nt
        union { _Float16 hx[8]; int4 v4; } cf;
        #pragma unroll
        for (int nt = 0; nt < 8; ++nt) cf.hx[nt] = (_Float16)rv[nt];
        int kc = l15 >> 2;
        int lf = (l15 & 3) * 16 + row;
        *(int4*)(h16 + (((size_t)tile * 4 + kc) * 64 + lf) * 8) = cf.v4;
    }

    if (write_ln) {
        float ga[8], be[8], wsv[8][8];
        #pragma unroll
        for (int nt = 0; nt < 8; ++nt) {
            int c = nt * 16 + l15;
            ga[nt] = gamma[c];
            be[nt] = beta[c];
            for (int j = 0; j < 8; ++j) wsv[nt][j] = ws[c * 8 + j];
        }
        float s = 0.f;
        #pragma unroll
        for (int nt = 0; nt < 8; ++nt) s += rv[nt];
        s += __shfl_xor(s, 1); s += __shfl_xor(s, 2);
        s += __shfl_xor(s, 4); s += __shfl_xor(s, 8);
        float mu = s * (1.0f / 128.0f);
        float var = 0.f;
        #pragma unroll
        for (int nt = 0; nt < 8; ++nt) { float d = rv[nt] - mu; var += d * d; }
        var += __shfl_xor(var, 1); var += __shfl_xor(var, 2);
        var += __shfl_xor(var, 4); var += __shfl_xor(var, 8);
        float rstd = rsqrtf(var * (1.0f / 128.0f) + LN_EPS);
        float lnv[8];
        #pragma unroll
        for (int nt = 0; nt < 8; ++nt)
            lnv[nt] = (rv[nt] - mu) * rstd * ga[nt] + be[nt];

        float ap[8];
        #pragma unroll
        for (int j = 0; j < 8; ++j) {
            float t = 0.f;
            for (int nt = 0; nt < 8; ++nt) t += lnv[nt] * wsv[nt][j];
            ap[j] = t;
        }
        #pragma unroll
        for (int j = 0; j < 8; ++j) {
            ap[j] += __shfl_xor(ap[j], 1); ap[j] += __shfl_xor(ap[j], 2);
            ap[j] += __shfl_xor(ap[j], 4); ap[j] += __shfl_xor(ap[j], 8);
        }
        if (l15 == 0) {
            for (int hh = 0; hh < 4; ++hh) {
                asw[node * 4 + hh] = ap[hh];
                adw[node * 4 + hh] = ap[4 + hh];
            }
        }

        int w0 = __builtin_amdgcn_cvt_pk_fp8_f32(lnv[0], lnv[1], 0, false);
        w0     = __builtin_amdgcn_cvt_pk_fp8_f32(lnv[2], lnv[3], w0, true);
        int w1 = __builtin_amdgcn_cvt_pk_fp8_f32(lnv[4], lnv[5], 0, false);
        w1     = __builtin_amdgcn_cvt_pk_fp8_f32(lnv[6], lnv[7], w1, true);
        *(int2*)(ln8w + (size_t)node * 128 + l15 * 8) = make_int2(w0, w1);
    }
}

// ---------------- output projection: fp16 MFMA streaming GEMM ----------------

__global__ __launch_bounds__(256) void k_out_proj_mfma(const _Float16* __restrict__ h16,
                                                       const _Float16* __restrict__ Bout,
                                                       const float* __restrict__ b,
                                                       float* __restrict__ out) {
    int tid = threadIdx.x;
    int lane = tid & 63;
    int tile = blockIdx.x * 4 + (tid >> 6);
    if (tile >= NT2) return;

    const _Float16* ab = h16 + (size_t)tile * 2048 + lane * 8;
    f32x4 acc[4];
    for (int nt = 0; nt < 4; ++nt) acc[nt] = (f32x4)(0.0f);
    #pragma unroll
    for (int kc = 0; kc < 4; ++kc) {
        half8 a = *(const half8*)(ab + kc * 512);
        #pragma unroll
        for (int nt = 0; nt < 4; ++nt) {
            half8 bf = *(const half8*)(Bout + ((size_t)(kc * 4 + nt) * 64 + lane) * 8);
            acc[nt] = __builtin_amdgcn_mfma_f32_16x16x32_f16(a, bf, acc[nt], 0, 0, 0);
        }
    }

    int l15 = lane & 15, quad = lane >> 4;
    float bo[4];
    #pragma unroll
    for (int nt = 0; nt < 4; ++nt) bo[nt] = b[nt * 16 + l15];
    #pragma unroll
    for (int r = 0; r < 4; ++r) {
        int node = tile * 16 + quad * 4 + r;
        float* orow = out + (size_t)node * OUTC;
        #pragma unroll
        for (int nt = 0; nt < 4; ++nt)
            orow[nt * 16 + l15] = acc[nt][r] + bo[nt];
    }
}

// ---------------- launch ----------------

extern "C" void kernel_launch(void* const* d_in, const int* in_sizes, int n_in,
                              void* d_out, int out_size, void* d_ws, size_t ws_size,
                              hipStream_t stream) {
    const float* x       = (const float*)d_in[0];
    const int*   ei      = (const int*)d_in[1];
    const float* W_in    = (const float*)d_in[2];
    const float* b_in    = (const float*)d_in[3];
    const float* W_conv  = (const float*)d_in[4];
    const float* att_src = (const float*)d_in[5];
    const float* att_dst = (const float*)d_in[6];
    const float* b_conv  = (const float*)d_in[7];
    const float* ln_g    = (const float*)d_in[8];
    const float* ln_b    = (const float*)d_in[9];
    const float* W_out   = (const float*)d_in[10];
    const float* b_out   = (const float*)d_in[11];
    float* out = (float*)d_out;

    char* ws = (char*)d_ws;
    size_t off = 0;
    auto alloc = [&](size_t bytes) { void* p = ws + off; off = (off + bytes + 255) & ~(size_t)255; return p; };
    float* h            = (float*)alloc((size_t)N_NODES * HID * 4);
    unsigned char* ln8a = (unsigned char*)alloc((size_t)N_NODES * 128);
    unsigned char* ln8b = (unsigned char*)alloc((size_t)N_NODES * 128);
    float* asa          = (float*)alloc((size_t)N_NODES * 4 * 4);
    float* asb          = (float*)alloc((size_t)N_NODES * 4 * 4);
    float* ada          = (float*)alloc((size_t)N_NODES * 4 * 4);
    float* adb          = (float*)alloc((size_t)N_NODES * 4 * 4);
    _Float16* Bp2       = (_Float16*)alloc((size_t)DEPTH * 65536 * 2);
    float* ws_all       = (float*)alloc((size_t)DEPTH * 1024 * 4);
    _Float16* h16       = (_Float16*)alloc((size_t)NT2 * 2048 * 2);   // out-proj A-frags
    _Float16* Bout      = (_Float16*)alloc((size_t)8192 * 2);         // out-proj B-frags
    int* deg    = (int*)alloc((size_t)N_NODES * 4);
    int* cur    = (int*)alloc((size_t)N_NODES * 4);
    int* row_ptr= (int*)alloc((size_t)(N_NODES + 1) * 4);
    int* csr    = (int*)alloc((size_t)E2 * 4);
    int* bsum   = (int*)alloc(256 * 4);
    (void)ws_size; (void)n_in; (void)in_sizes; (void)out_size;

    hipMemsetAsync(deg, 0, (size_t)N_NODES * 4, stream);
    hipMemsetAsync(cur, 0, (size_t)N_NODES * 4, stream);

    // CSR build
    k_deg<<<(E2 + 255) / 256, 256, 0, stream>>>(ei, deg);
    int nb = (N_NODES + 1023) / 1024;
    k_scan_block<<<nb, 1024, 0, stream>>>(deg, row_ptr, bsum, N_NODES);
    k_scan_bsum<<<1, 64, 0, stream>>>(bsum, nb);
    k_scan_fix<<<nb, 1024, 0, stream>>>(deg, row_ptr, bsum, N_NODES);
    k_fill<<<(E2 + 255) / 256, 256, 0, stream>>>(ei, row_ptr, cur, csr);

    // weight preprocessing (per call; graph-safe)
    k_ws<<<(DEPTH * 1024 + 255) / 256, 256, 0, stream>>>(W_conv, att_src, att_dst, ws_all);
    k_repackB2<<<(DEPTH * 65536 + 255) / 256, 256, 0, stream>>>(W_conv, Bp2);
    k_repackBout<<<32, 256, 0, stream>>>(W_out, Bout);

    // input projection + first LN (fp8 table + layer-0 alphas) into ping buffer A
    k_in_proj_ln<<<N_NODES / 4, 256, 0, stream>>>(x, W_in, b_in, ln_g, ln_b, ws_all,
                                                  h, ln8a, asa, ada);

    // fused layers (ping-pong ln8/as/ad between layers)
    for (int i = 0; i < DEPTH; ++i) {
        const float* bcp = b_conv + (size_t)i * HID;
        int write_ln = (i + 1 < DEPTH) ? 1 : 0;
        int last = (i + 1 == DEPTH) ? 1 : 0;
        int nl = (i + 1 < DEPTH) ? i + 1 : i;
        const float* gp = ln_g + (size_t)nl * HID;
        const float* bp = ln_b + (size_t)nl * HID;
        const float* wsp = ws_all + (size_t)nl * 1024;

        const unsigned char* l8r = (i & 1) ? ln8b : ln8a;
        unsigned char*       l8w = (i & 1) ? ln8a : ln8b;
        const float* asr = (i & 1) ? asb : asa;
        float*       asw = (i & 1) ? asa : asb;
        const float* adr = (i & 1) ? adb : ada;
        float*       adw = (i & 1) ? ada : adb;

        k_layer<<<NT2, 256, 0, stream>>>(l8r, row_ptr, csr, asr, adr,
                                         Bp2 + (size_t)i * 65536, wsp,
                                         bcp, gp, bp, h, l8w, asw, adw,
                                         h16, write_ln, last);
    }

    k_out_proj_mfma<<<(NT2 + 3) / 4, 256, 0, stream>>>(h16, Bout, b_out, out);
}